// Round 15
// baseline (3103.466 us; speedup 1.0000x reference)
//
#include <hip/hip_runtime.h>
#include <hip/hip_bf16.h>
#include <stdint.h>

// Problem constants (fixed by setup_inputs)
#define E_NUM 8
#define CHUNK 4096
#define HDIM  2048
#define IDIM  8192

typedef __bf16 bf16x8 __attribute__((ext_vector_type(8)));
typedef __bf16 bf16x4 __attribute__((ext_vector_type(4)));
typedef float  f32x4  __attribute__((ext_vector_type(4)));

#define GLDS16(g, l) __builtin_amdgcn_global_load_lds(                         \
    (const __attribute__((address_space(1))) void*)(g),                        \
    (__attribute__((address_space(3))) void*)(l), 16, 0, 0)
#define MFMA(a, b, c) __builtin_amdgcn_mfma_f32_16x16x32_bf16((a), (b), (c), 0, 0, 0)
#define FENCE() asm volatile("" ::: "memory")
#define BAR()   do { FENCE(); __builtin_amdgcn_s_barrier(); FENCE(); } while (0)
#define WAITV(n) asm volatile("s_waitcnt vmcnt(" #n ")" ::: "memory")

// frag read from a 128-row x 128B LDS region; 3-bit XOR swizzle (conflict-free)
#define RDF(base, rp, ks) \
  (*(const bf16x8*)((base) + (rp) * 128 + ((((ks) * 64) + q16) ^ (((rp) & 7) << 4))))

// ---------------------------------------------------------------------------
// f32 -> bf16 conversion (memory-bound, 8 elems/thread)
// ---------------------------------------------------------------------------
__global__ __launch_bounds__(256) void cvt_kernel(
    const float* __restrict__ src, __bf16* __restrict__ dst)
{
  const size_t i = ((size_t)blockIdx.x * 256 + threadIdx.x) * 8;
  float4 a = *reinterpret_cast<const float4*>(src + i);
  float4 b = *reinterpret_cast<const float4*>(src + i + 4);
  bf16x8 r;
  r[0] = (__bf16)a.x; r[1] = (__bf16)a.y; r[2] = (__bf16)a.z; r[3] = (__bf16)a.w;
  r[4] = (__bf16)b.x; r[5] = (__bf16)b.y; r[6] = (__bf16)b.z; r[7] = (__bf16)b.w;
  *reinterpret_cast<bf16x8*>(dst + i) = r;
}

// ===========================================================================
// Pipelined fused gate+up GEMM (r14 structure; ALL later-consumer LDS reads
// moved between stage and batch-2 so batch-2 MFMAs hide read latency and
// every region ENDS on MFMA -> clean pipe handoff at the barrier).
// BM=256 x BN=128, BK=64. 8 waves (4M x 2N).
// LDS/buffer (64KB): Ah0@0, Ah1@16K, G@32K, U@48K (each 128 rows x 128B).
// Region A: read aF1 | MFMA aF0xwG | stage so.{Ah1,U}[kt+1] | read wU | MFMA aF1xwG
// Region B: MFMA aF0xwU | stage sb.{Ah0,G}[kt+2] | read aF0',wG' | MFMA aF1xwU
// vmcnt: each region issues 4 loads; at region entry pending=8, reads need
// the oldest 4 -> WAITV(4); WAITV(0) at kt=NT-1. Stage order preserved ->
// identical pending sets at every WAITV. Re-stage distances >=2 barriers.
// NOTE (r8-r10): no pointer-array hoisting, no body duplication (scratch!).
// ===========================================================================
__global__ __launch_bounds__(512, 2) void gateup8_kernel(
    const __bf16* __restrict__ X, const __bf16* __restrict__ Gw,
    const __bf16* __restrict__ Uw, __bf16* __restrict__ act)
{
  extern __shared__ char smem[];   // 2 x 64KB
  const int tid  = threadIdx.x;
  const int lane = tid & 63;
  const int wave = tid >> 6;
  const int wm = wave >> 1, wn = wave & 1;
  const int e  = blockIdx.z;
  const int m0 = e * CHUNK + blockIdx.y * 256;   // row into X/act
  const int n0 = e * IDIM  + blockIdx.x * 128;   // row into Gw/Uw

  int su[2], skk[2];
#pragma unroll
  for (int j = 0; j < 2; ++j) {
    int P = j * 8192 + tid * 16;
    int L = P ^ (((P >> 7) & 7) << 4);   // same 3-bit involution as RDF
    su[j]  = L >> 7;
    skk[j] = (L & 127) >> 1;
  }
  const int ldsw = wave * 1024;

  auto stageA = [&](char* bb, int h, int kt2) {
#pragma unroll
    for (int j = 0; j < 2; ++j) {
      int u = su[j];
      int r = (u & 31) + h * 32 + (u >> 5) * 64;
      const __bf16* src = X + (size_t)(m0 + r) * HDIM + kt2 * 64 + skk[j];
      GLDS16(src, bb + h * 16384 + j * 8192 + ldsw);
    }
  };
  auto stageW = [&](char* bb, int w, int kt2) {   // w: 0=G, 1=U
    const __bf16* W = w ? Uw : Gw;
#pragma unroll
    for (int j = 0; j < 2; ++j) {
      const __bf16* src = W + (size_t)(n0 + su[j]) * HDIM + kt2 * 64 + skk[j];
      GLDS16(src, bb + 32768 + w * 16384 + j * 8192 + ldsw);
    }
  };

  f32x4 accg[4][4], accu[4][4];
#pragma unroll
  for (int m = 0; m < 4; ++m)
#pragma unroll
    for (int n = 0; n < 4; ++n)
#pragma unroll
      for (int j = 0; j < 4; ++j) { accg[m][n][j] = 0.f; accu[m][n][j] = 0.f; }

  const int frow = lane & 15;
  const int q16  = (lane >> 4) * 16;
  const int NT   = HDIM / 64;   // 32

  bf16x8 aF0[2][2], aF1[2][2], wG[4][2], wU[4][2];

  // ---- prologue: land Ah0[0],G[0]; read aF0,wG; queue 8 loads (4 units) ----
  {
    char* s0 = smem;
    char* s1 = smem + 65536;
    stageA(s0, 0, 0); stageW(s0, 0, 0);
    WAITV(0);
    BAR();
#pragma unroll
    for (int m = 0; m < 2; ++m) { int rp = wm * 32 + m * 16 + frow;
      aF0[m][0] = RDF(s0, rp, 0); aF0[m][1] = RDF(s0, rp, 1); }
#pragma unroll
    for (int n = 0; n < 4; ++n) { int rp = wn * 64 + n * 16 + frow;
      wG[n][0] = RDF(s0 + 32768, rp, 0); wG[n][1] = RDF(s0 + 32768, rp, 1); }
    stageA(s0, 1, 0);   // Ah1[0]
    stageW(s0, 1, 0);   // U[0]
    stageA(s1, 0, 1);   // Ah0[1]
    stageW(s1, 0, 1);   // G[1]
  }

  for (int kt = 0; kt < NT; ++kt) {
    char* sb = smem + (kt & 1) * 65536;
    char* so = smem + ((kt & 1) ^ 1) * 65536;

    // ========== region A: g-MFMAs ==========
    if (kt + 1 < NT) { WAITV(4); } else { WAITV(0); }
    BAR();
#pragma unroll
    for (int m = 0; m < 2; ++m) { int rp = wm * 32 + m * 16 + frow;
      aF1[m][0] = RDF(sb + 16384, rp, 0); aF1[m][1] = RDF(sb + 16384, rp, 1); }
    __builtin_amdgcn_s_setprio(1);
#pragma unroll
    for (int n = 0; n < 4; ++n)
#pragma unroll
      for (int m = 0; m < 2; ++m) {
        accg[m][n] = MFMA(aF0[m][0], wG[n][0], accg[m][n]);
        accg[m][n] = MFMA(aF0[m][1], wG[n][1], accg[m][n]);
      }
    __builtin_amdgcn_s_setprio(0);
    if (kt + 1 < NT) { stageA(so, 1, kt + 1); stageW(so, 1, kt + 1); }
#pragma unroll
    for (int n = 0; n < 4; ++n) { int rp = wn * 64 + n * 16 + frow;
      wU[n][0] = RDF(sb + 49152, rp, 0); wU[n][1] = RDF(sb + 49152, rp, 1); }
    __builtin_amdgcn_s_setprio(1);
#pragma unroll
    for (int n = 0; n < 4; ++n)
#pragma unroll
      for (int m = 0; m < 2; ++m) {
        accg[2 + m][n] = MFMA(aF1[m][0], wG[n][0], accg[2 + m][n]);
        accg[2 + m][n] = MFMA(aF1[m][1], wG[n][1], accg[2 + m][n]);
      }
    __builtin_amdgcn_s_setprio(0);

    // ========== region B: u-MFMAs ==========
    if (kt + 1 < NT) { WAITV(4); } else { WAITV(0); }
    BAR();
    __builtin_amdgcn_s_setprio(1);
#pragma unroll
    for (int n = 0; n < 4; ++n)
#pragma unroll
      for (int m = 0; m < 2; ++m) {
        accu[m][n] = MFMA(aF0[m][0], wU[n][0], accu[m][n]);
        accu[m][n] = MFMA(aF0[m][1], wU[n][1], accu[m][n]);
      }
    __builtin_amdgcn_s_setprio(0);
    if (kt + 2 < NT) { stageA(sb, 0, kt + 2); stageW(sb, 0, kt + 2); }
    if (kt + 1 < NT) {
#pragma unroll
      for (int m = 0; m < 2; ++m) { int rp = wm * 32 + m * 16 + frow;
        aF0[m][0] = RDF(so, rp, 0); aF0[m][1] = RDF(so, rp, 1); }
#pragma unroll
      for (int n = 0; n < 4; ++n) { int rp = wn * 64 + n * 16 + frow;
        wG[n][0] = RDF(so + 32768, rp, 0); wG[n][1] = RDF(so + 32768, rp, 1); }
    }
    __builtin_amdgcn_s_setprio(1);
#pragma unroll
    for (int n = 0; n < 4; ++n)
#pragma unroll
      for (int m = 0; m < 2; ++m) {
        accu[2 + m][n] = MFMA(aF1[m][0], wU[n][0], accu[2 + m][n]);
        accu[2 + m][n] = MFMA(aF1[m][1], wU[n][1], accu[2 + m][n]);
      }
    __builtin_amdgcn_s_setprio(0);
  }

  // epilogue: silu(g)*u -> bf16 act
  const int orow0 = m0 + wm * 64 + (lane >> 4) * 4;
  const int ocol0 = blockIdx.x * 128 + wn * 64 + frow;
#pragma unroll
  for (int m = 0; m < 4; ++m)
#pragma unroll
    for (int n = 0; n < 4; ++n)
#pragma unroll
      for (int j = 0; j < 4; ++j) {
        float g = accg[m][n][j];
        float u = accu[m][n][j];
        float s = g / (1.0f + __expf(-g));
        act[(size_t)(orow0 + m * 16 + j) * IDIM + (ocol0 + n * 16)] = (__bf16)(s * u);
      }
}

// ===========================================================================
// Pipelined down GEMM: out = act . Dw^T (f32). BM=256 x BN=256, BK=64.
// Identical merged-region skeleton (bN0/bN1 in the wG/wU roles), same
// reads-before-batch-2 ordering.
// ===========================================================================
__global__ __launch_bounds__(512, 2) void down8_kernel(
    const __bf16* __restrict__ act, const __bf16* __restrict__ Dw,
    float* __restrict__ out)
{
  extern __shared__ char smem[];
  const int tid  = threadIdx.x;
  const int lane = tid & 63;
  const int wave = tid >> 6;
  const int wm = wave >> 1, wc = wave & 1;
  const int e  = blockIdx.z;
  const int m0 = e * CHUNK + blockIdx.y * 256;   // row into act/out
  const int n0 = e * HDIM  + blockIdx.x * 256;   // row into Dw

  int su[2], skk[2];
#pragma unroll
  for (int j = 0; j < 2; ++j) {
    int P = j * 8192 + tid * 16;
    int L = P ^ (((P >> 7) & 7) << 4);
    su[j]  = L >> 7;
    skk[j] = (L & 127) >> 1;
  }
  const int ldsw = wave * 1024;

  auto stageA = [&](char* bb, int h, int kt2) {
#pragma unroll
    for (int j = 0; j < 2; ++j) {
      int u = su[j];
      int r = (u & 31) + h * 32 + (u >> 5) * 64;
      const __bf16* src = act + (size_t)(m0 + r) * IDIM + kt2 * 64 + skk[j];
      GLDS16(src, bb + h * 16384 + j * 8192 + ldsw);
    }
  };
  auto stageB = [&](char* bb, int h, int kt2) {   // Dw half h
#pragma unroll
    for (int j = 0; j < 2; ++j) {
      int u = su[j];
      int r = (u & 63) + h * 64 + (u >> 6) * 128;
      const __bf16* src = Dw + (size_t)(n0 + r) * IDIM + kt2 * 64 + skk[j];
      GLDS16(src, bb + 32768 + h * 16384 + j * 8192 + ldsw);
    }
  };

  f32x4 accn0[4][4], accn1[4][4];
#pragma unroll
  for (int m = 0; m < 4; ++m)
#pragma unroll
    for (int n = 0; n < 4; ++n)
#pragma unroll
      for (int j = 0; j < 4; ++j) { accn0[m][n][j] = 0.f; accn1[m][n][j] = 0.f; }

  const int frow = lane & 15;
  const int q16  = (lane >> 4) * 16;
  const int NT   = IDIM / 64;   // 128

  bf16x8 aF0[2][2], aF1[2][2], bN0[4][2], bN1[4][2];

  {
    char* s0 = smem;
    char* s1 = smem + 65536;
    stageA(s0, 0, 0); stageB(s0, 0, 0);
    WAITV(0);
    BAR();
#pragma unroll
    for (int m = 0; m < 2; ++m) { int rp = wm * 32 + m * 16 + frow;
      aF0[m][0] = RDF(s0, rp, 0); aF0[m][1] = RDF(s0, rp, 1); }
#pragma unroll
    for (int n = 0; n < 4; ++n) { int rp = wc * 64 + n * 16 + frow;
      bN0[n][0] = RDF(s0 + 32768, rp, 0); bN0[n][1] = RDF(s0 + 32768, rp, 1); }
    stageA(s0, 1, 0);   // Ah1[0]
    stageB(s0, 1, 0);   // B1[0]
    stageA(s1, 0, 1);   // Ah0[1]
    stageB(s1, 0, 1);   // B0[1]
  }

  for (int kt = 0; kt < NT; ++kt) {
    char* sb = smem + (kt & 1) * 65536;
    char* so = smem + ((kt & 1) ^ 1) * 65536;

    // ========== region A ==========
    if (kt + 1 < NT) { WAITV(4); } else { WAITV(0); }
    BAR();
#pragma unroll
    for (int m = 0; m < 2; ++m) { int rp = wm * 32 + m * 16 + frow;
      aF1[m][0] = RDF(sb + 16384, rp, 0); aF1[m][1] = RDF(sb + 16384, rp, 1); }
    __builtin_amdgcn_s_setprio(1);
#pragma unroll
    for (int n = 0; n < 4; ++n)
#pragma unroll
      for (int m = 0; m < 2; ++m) {
        accn0[m][n] = MFMA(aF0[m][0], bN0[n][0], accn0[m][n]);
        accn0[m][n] = MFMA(aF0[m][1], bN0[n][1], accn0[m][n]);
      }
    __builtin_amdgcn_s_setprio(0);
    if (kt + 1 < NT) { stageA(so, 1, kt + 1); stageB(so, 1, kt + 1); }
#pragma unroll
    for (int n = 0; n < 4; ++n) { int rp = wc * 64 + n * 16 + frow;
      bN1[n][0] = RDF(sb + 49152, rp, 0); bN1[n][1] = RDF(sb + 49152, rp, 1); }
    __builtin_amdgcn_s_setprio(1);
#pragma unroll
    for (int n = 0; n < 4; ++n)
#pragma unroll
      for (int m = 0; m < 2; ++m) {
        accn0[2 + m][n] = MFMA(aF1[m][0], bN0[n][0], accn0[2 + m][n]);
        accn0[2 + m][n] = MFMA(aF1[m][1], bN0[n][1], accn0[2 + m][n]);
      }
    __builtin_amdgcn_s_setprio(0);

    // ========== region B ==========
    if (kt + 1 < NT) { WAITV(4); } else { WAITV(0); }
    BAR();
    __builtin_amdgcn_s_setprio(1);
#pragma unroll
    for (int n = 0; n < 4; ++n)
#pragma unroll
      for (int m = 0; m < 2; ++m) {
        accn1[m][n] = MFMA(aF0[m][0], bN1[n][0], accn1[m][n]);
        accn1[m][n] = MFMA(aF0[m][1], bN1[n][1], accn1[m][n]);
      }
    __builtin_amdgcn_s_setprio(0);
    if (kt + 2 < NT) { stageA(sb, 0, kt + 2); stageB(sb, 0, kt + 2); }
    if (kt + 1 < NT) {
#pragma unroll
      for (int m = 0; m < 2; ++m) { int rp = wm * 32 + m * 16 + frow;
        aF0[m][0] = RDF(so, rp, 0); aF0[m][1] = RDF(so, rp, 1); }
#pragma unroll
      for (int n = 0; n < 4; ++n) { int rp = wc * 64 + n * 16 + frow;
        bN0[n][0] = RDF(so + 32768, rp, 0); bN0[n][1] = RDF(so + 32768, rp, 1); }
    }
    __builtin_amdgcn_s_setprio(1);
#pragma unroll
    for (int n = 0; n < 4; ++n)
#pragma unroll
      for (int m = 0; m < 2; ++m) {
        accn1[2 + m][n] = MFMA(aF1[m][0], bN1[n][0], accn1[2 + m][n]);
        accn1[2 + m][n] = MFMA(aF1[m][1], bN1[n][1], accn1[2 + m][n]);
      }
    __builtin_amdgcn_s_setprio(0);
  }

  const int orow0 = m0 + wm * 64 + (lane >> 4) * 4;
  const int ocol0 = blockIdx.x * 256 + wc * 128 + frow;
#pragma unroll
  for (int m = 0; m < 4; ++m)
#pragma unroll
    for (int n = 0; n < 4; ++n)
#pragma unroll
      for (int j = 0; j < 4; ++j) {
        out[(size_t)(orow0 + m * 16 + j) * HDIM + (ocol0 + n * 16)] = accn0[m][n][j];
        out[(size_t)(orow0 + m * 16 + j) * HDIM + (ocol0 + 64 + n * 16)] = accn1[m][n][j];
      }
}

// ===========================================================================
// Fallback: round-3 kernels (128^2 2-barrier, per-expert) if ws is small.
// ===========================================================================
__global__ __launch_bounds__(256) void gateup2_kernel(
    const __bf16* __restrict__ X, const __bf16* __restrict__ Gw,
    const __bf16* __restrict__ Uw, __bf16* __restrict__ act)
{
  __shared__ __bf16 lds[2][3][128 * 32];
  const int tid  = threadIdx.x;
  const int lane = tid & 63;
  const int wave = tid >> 6;
  const int wr = wave >> 1, wc = wave & 1;
  const int m0 = blockIdx.x * 128;
  const int n0 = blockIdx.y * 128;

  int srow[2], scol[2];
#pragma unroll
  for (int h = 0; h < 2; ++h) {
    const int B  = h * 4096 + tid * 16;
    const int Bs = B ^ (((B >> 7) & 3) << 4);
    srow[h] = Bs >> 6;
    scol[h] = (Bs & 63) >> 1;
  }
  const int ldst_off[2] = { wave * 1024, 4096 + wave * 1024 };

  f32x4 accg[4][4], accu[4][4];
#pragma unroll
  for (int m = 0; m < 4; ++m)
#pragma unroll
    for (int n = 0; n < 4; ++n)
#pragma unroll
      for (int j = 0; j < 4; ++j) { accg[m][n][j] = 0.f; accu[m][n][j] = 0.f; }

  const int frow  = lane & 15;
  const int rdoff = ((lane >> 4) * 16) ^ (((frow >> 1) & 3) << 4);

  auto stage = [&](int buf, int kt) {
    const int k0 = kt * 32;
#pragma unroll
    for (int h = 0; h < 2; ++h) {
      GLDS16(X  + (size_t)(m0 + srow[h]) * HDIM + k0 + scol[h], (char*)&lds[buf][0][0] + ldst_off[h]);
      GLDS16(Gw + (size_t)(n0 + srow[h]) * HDIM + k0 + scol[h], (char*)&lds[buf][1][0] + ldst_off[h]);
      GLDS16(Uw + (size_t)(n0 + srow[h]) * HDIM + k0 + scol[h], (char*)&lds[buf][2][0] + ldst_off[h]);
    }
  };

  const int NT = HDIM / 32;
  stage(0, 0);
  int cur = 0;
  for (int kt = 0; kt < NT; ++kt) {
    __syncthreads();
    if (kt + 1 < NT) stage(cur ^ 1, kt + 1);
    const char* bA = (const char*)&lds[cur][0][0];
    const char* bG = (const char*)&lds[cur][1][0];
    const char* bU = (const char*)&lds[cur][2][0];
    bf16x8 af[4];
#pragma unroll
    for (int m = 0; m < 4; ++m)
      af[m] = *(const bf16x8*)(bA + (wr * 64 + m * 16 + frow) * 64 + rdoff);
#pragma unroll
    for (int n = 0; n < 4; ++n) {
      bf16x8 bg = *(const bf16x8*)(bG + (wc * 64 + n * 16 + frow) * 64 + rdoff);
      bf16x8 bu = *(const bf16x8*)(bU + (wc * 64 + n * 16 + frow) * 64 + rdoff);
#pragma unroll
      for (int m = 0; m < 4; ++m) {
        accg[m][n] = MFMA(af[m], bg, accg[m][n]);
        accu[m][n] = MFMA(af[m], bu, accu[m][n]);
      }
    }
    cur ^= 1;
  }
  const int orow = m0 + wr * 64 + (lane >> 4) * 4;
  const int ocol = n0 + wc * 64 + (lane & 15);
#pragma unroll
  for (int m = 0; m < 4; ++m)
#pragma unroll
    for (int n = 0; n < 4; ++n)
#pragma unroll
      for (int j = 0; j < 4; ++j) {
        float g = accg[m][n][j];
        float u = accu[m][n][j];
        float s = g / (1.0f + __expf(-g));
        act[(size_t)(orow + m * 16 + j) * IDIM + (ocol + n * 16)] = (__bf16)(s * u);
      }
}

__global__ __launch_bounds__(256) void down2_kernel(
    const __bf16* __restrict__ act, const __bf16* __restrict__ Dw,
    float* __restrict__ out)
{
  __shared__ __bf16 lds[2][2][128 * 32];
  const int tid  = threadIdx.x;
  const int lane = tid & 63;
  const int wave = tid >> 6;
  const int wr = wave >> 1, wc = wave & 1;
  const int m0 = blockIdx.x * 128;
  const int n0 = blockIdx.y * 128;

  int srow[2], scol[2];
#pragma unroll
  for (int h = 0; h < 2; ++h) {
    const int B  = h * 4096 + tid * 16;
    const int Bs = B ^ (((B >> 7) & 3) << 4);
    srow[h] = Bs >> 6;
    scol[h] = (Bs & 63) >> 1;
  }
  const int ldst_off[2] = { wave * 1024, 4096 + wave * 1024 };

  f32x4 acc[4][4];
#pragma unroll
  for (int m = 0; m < 4; ++m)
#pragma unroll
    for (int n = 0; n < 4; ++n)
#pragma unroll
      for (int j = 0; j < 4; ++j) acc[m][n][j] = 0.f;

  const int frow  = lane & 15;
  const int rdoff = ((lane >> 4) * 16) ^ (((frow >> 1) & 3) << 4);

  auto stage = [&](int buf, int kt) {
    const int k0 = kt * 32;
#pragma unroll
    for (int h = 0; h < 2; ++h) {
      GLDS16(act + (size_t)(m0 + srow[h]) * IDIM + k0 + scol[h], (char*)&lds[buf][0][0] + ldst_off[h]);
      GLDS16(Dw  + (size_t)(n0 + srow[h]) * IDIM + k0 + scol[h], (char*)&lds[buf][1][0] + ldst_off[h]);
    }
  };

  const int NT = IDIM / 32;
  stage(0, 0);
  int cur = 0;
  for (int kt = 0; kt < NT; ++kt) {
    __syncthreads();
    if (kt + 1 < NT) stage(cur ^ 1, kt + 1);
    const char* bA = (const char*)&lds[cur][0][0];
    const char* bW = (const char*)&lds[cur][1][0];
    bf16x8 af[4];
#pragma unroll
    for (int m = 0; m < 4; ++m)
      af[m] = *(const bf16x8*)(bA + (wr * 64 + m * 16 + frow) * 64 + rdoff);
#pragma unroll
    for (int n = 0; n < 4; ++n) {
      bf16x8 bw = *(const bf16x8*)(bW + (wc * 64 + n * 16 + frow) * 64 + rdoff);
#pragma unroll
      for (int m = 0; m < 4; ++m)
        acc[m][n] = MFMA(af[m], bw, acc[m][n]);
    }
    cur ^= 1;
  }
  const int orow = m0 + wr * 64 + (lane >> 4) * 4;
  const int ocol = n0 + wc * 64 + (lane & 15);
#pragma unroll
  for (int m = 0; m < 4; ++m)
#pragma unroll
    for (int n = 0; n < 4; ++n)
#pragma unroll
      for (int j = 0; j < 4; ++j)
        out[(size_t)(orow + m * 16 + j) * HDIM + (ocol + n * 16)] = acc[m][n][j];
}

// ---------------------------------------------------------------------------
extern "C" void kernel_launch(void* const* d_in, const int* in_sizes, int n_in,
                              void* d_out, int out_size, void* d_ws, size_t ws_size,
                              hipStream_t stream)
{
  const float* hidden = (const float*)d_in[0];
  const float* gate_w = (const float*)d_in[1];
  const float* up_w   = (const float*)d_in[2];
  const float* down_w = (const float*)d_in[3];
  float* out = (float*)d_out;

  const size_t SZ_X    = (size_t)32768 * HDIM;
  const size_t SZ_Wall = (size_t)E_NUM * IDIM * HDIM;
  const size_t SZ_ACT  = (size_t)32768 * IDIM;
  const size_t need8 = (SZ_X + 3 * SZ_Wall + SZ_ACT) * sizeof(__bf16);  // ~1.48 GB

  if (ws_size >= need8) {
    __bf16* xb  = (__bf16*)d_ws;
    __bf16* gwb = xb  + SZ_X;
    __bf16* uwb = gwb + SZ_Wall;
    __bf16* dwb = uwb + SZ_Wall;
    __bf16* actb = dwb + SZ_Wall;

    cvt_kernel<<<SZ_X    / 2048, 256, 0, stream>>>(hidden, xb);
    cvt_kernel<<<SZ_Wall / 2048, 256, 0, stream>>>(gate_w, gwb);
    cvt_kernel<<<SZ_Wall / 2048, 256, 0, stream>>>(up_w,   uwb);
    cvt_kernel<<<SZ_Wall / 2048, 256, 0, stream>>>(down_w, dwb);

    gateup8_kernel<<<dim3(IDIM / 128, CHUNK / 256, E_NUM), 512, 131072, stream>>>(xb, gwb, uwb, actb);
    down8_kernel  <<<dim3(HDIM / 256, CHUNK / 256, E_NUM), 512, 131072, stream>>>(actb, dwb, out);
  } else {
    const size_t sX = (size_t)CHUNK * HDIM;
    const size_t sW = (size_t)IDIM * HDIM;
    __bf16* xb = (__bf16*)d_ws;
    __bf16* gb = xb + sX;
    __bf16* ub = gb + sW;
    __bf16* db = ub + sW;
    __bf16* act = db + sW;
    for (int e = 0; e < E_NUM; ++e) {
      const float* Xe = hidden + (size_t)e * sX;
      const float* Ge = gate_w + (size_t)e * sW;
      const float* Ue = up_w   + (size_t)e * sW;
      const float* De = down_w + (size_t)e * sW;
      float* Oe = out + (size_t)e * CHUNK * HDIM;
      cvt_kernel<<<sX / 2048, 256, 0, stream>>>(Xe, xb);
      cvt_kernel<<<sW / 2048, 256, 0, stream>>>(Ge, gb);
      cvt_kernel<<<sW / 2048, 256, 0, stream>>>(Ue, ub);
      cvt_kernel<<<sW / 2048, 256, 0, stream>>>(De, db);
      gateup2_kernel<<<dim3(CHUNK / 128, IDIM / 128), 256, 0, stream>>>(xb, gb, ub, act);
      down2_kernel<<<dim3(CHUNK / 128, HDIM / 128), 256, 0, stream>>>(act, db, Oe);
    }
  }
}

// Round 16
// 3056.914 us; speedup vs baseline: 1.0152x; 1.0152x over previous
//
#include <hip/hip_runtime.h>
#include <hip/hip_bf16.h>
#include <stdint.h>

// Problem constants (fixed by setup_inputs)
#define E_NUM 8
#define CHUNK 4096
#define HDIM  2048
#define IDIM  8192

typedef __bf16 bf16x8 __attribute__((ext_vector_type(8)));
typedef __bf16 bf16x4 __attribute__((ext_vector_type(4)));
typedef float  f32x4  __attribute__((ext_vector_type(4)));

#define GLDS16(g, l) __builtin_amdgcn_global_load_lds(                         \
    (const __attribute__((address_space(1))) void*)(g),                        \
    (__attribute__((address_space(3))) void*)(l), 16, 0, 0)
#define MFMA(a, b, c) __builtin_amdgcn_mfma_f32_16x16x32_bf16((a), (b), (c), 0, 0, 0)
#define FENCE() asm volatile("" ::: "memory")
#define BAR()   do { FENCE(); __builtin_amdgcn_s_barrier(); FENCE(); } while (0)
#define WAITV(n) asm volatile("s_waitcnt vmcnt(" #n ")" ::: "memory")

// frag read from a 128-row x 128B LDS region; 3-bit XOR swizzle (conflict-free)
#define RDF(base, rp, ks) \
  (*(const bf16x8*)((base) + (rp) * 128 + ((((ks) * 64) + q16) ^ (((rp) & 7) << 4))))

// ---------------------------------------------------------------------------
// f32 -> bf16 conversion (memory-bound, 8 elems/thread)
// ---------------------------------------------------------------------------
__global__ __launch_bounds__(256) void cvt_kernel(
    const float* __restrict__ src, __bf16* __restrict__ dst)
{
  const size_t i = ((size_t)blockIdx.x * 256 + threadIdx.x) * 8;
  float4 a = *reinterpret_cast<const float4*>(src + i);
  float4 b = *reinterpret_cast<const float4*>(src + i + 4);
  bf16x8 r;
  r[0] = (__bf16)a.x; r[1] = (__bf16)a.y; r[2] = (__bf16)a.z; r[3] = (__bf16)a.w;
  r[4] = (__bf16)b.x; r[5] = (__bf16)b.y; r[6] = (__bf16)b.z; r[7] = (__bf16)b.w;
  *reinterpret_cast<bf16x8*>(dst + i) = r;
}

// ===========================================================================
// Pipelined fused gate+up GEMM (round-14 structure — BEST KNOWN, 3.069 ms
// total). 2 barriers/K-tile; stage issued AFTER the first MFMA batch so the
// matrix pipe starts immediately post-barrier; stage VALU overlaps batch-1.
// BM=256 x BN=128, BK=64. 8 waves (4M x 2N).
// LDS/buffer (64KB): Ah0@0, Ah1@16K, G@32K, U@48K (each 128 rows x 128B).
// Region A: read aF1 | MFMA aF0xwG | stage so.{Ah1,U}[kt+1] | MFMA aF1xwG | read wU
// Region B: MFMA aF0xwU | stage sb.{Ah0,G}[kt+2] | read aF0' | MFMA aF1xwU | read wG'
// vmcnt: each region issues 4 loads; at region entry pending=8, reads need
// the oldest 4 -> WAITV(4); WAITV(0) at kt=NT-1.
// NOTE (r8-r10): no pointer-array hoisting, no body duplication (scratch!).
// NOTE (r15): moving the trailing reads before batch-2 was slightly negative
// (live-range growth) — keep reads trailing as here.
// ===========================================================================
__global__ __launch_bounds__(512, 2) void gateup8_kernel(
    const __bf16* __restrict__ X, const __bf16* __restrict__ Gw,
    const __bf16* __restrict__ Uw, __bf16* __restrict__ act)
{
  extern __shared__ char smem[];   // 2 x 64KB
  const int tid  = threadIdx.x;
  const int lane = tid & 63;
  const int wave = tid >> 6;
  const int wm = wave >> 1, wn = wave & 1;
  const int e  = blockIdx.z;
  const int m0 = e * CHUNK + blockIdx.y * 256;   // row into X/act
  const int n0 = e * IDIM  + blockIdx.x * 128;   // row into Gw/Uw

  int su[2], skk[2];
#pragma unroll
  for (int j = 0; j < 2; ++j) {
    int P = j * 8192 + tid * 16;
    int L = P ^ (((P >> 7) & 7) << 4);   // same 3-bit involution as RDF
    su[j]  = L >> 7;
    skk[j] = (L & 127) >> 1;
  }
  const int ldsw = wave * 1024;

  auto stageA = [&](char* bb, int h, int kt2) {
#pragma unroll
    for (int j = 0; j < 2; ++j) {
      int u = su[j];
      int r = (u & 31) + h * 32 + (u >> 5) * 64;
      const __bf16* src = X + (size_t)(m0 + r) * HDIM + kt2 * 64 + skk[j];
      GLDS16(src, bb + h * 16384 + j * 8192 + ldsw);
    }
  };
  auto stageW = [&](char* bb, int w, int kt2) {   // w: 0=G, 1=U
    const __bf16* W = w ? Uw : Gw;
#pragma unroll
    for (int j = 0; j < 2; ++j) {
      const __bf16* src = W + (size_t)(n0 + su[j]) * HDIM + kt2 * 64 + skk[j];
      GLDS16(src, bb + 32768 + w * 16384 + j * 8192 + ldsw);
    }
  };

  f32x4 accg[4][4], accu[4][4];
#pragma unroll
  for (int m = 0; m < 4; ++m)
#pragma unroll
    for (int n = 0; n < 4; ++n)
#pragma unroll
      for (int j = 0; j < 4; ++j) { accg[m][n][j] = 0.f; accu[m][n][j] = 0.f; }

  const int frow = lane & 15;
  const int q16  = (lane >> 4) * 16;
  const int NT   = HDIM / 64;   // 32

  bf16x8 aF0[2][2], aF1[2][2], wG[4][2], wU[4][2];

  // ---- prologue: land Ah0[0],G[0]; read aF0,wG; queue 8 loads (4 units) ----
  {
    char* s0 = smem;
    char* s1 = smem + 65536;
    stageA(s0, 0, 0); stageW(s0, 0, 0);
    WAITV(0);
    BAR();
#pragma unroll
    for (int m = 0; m < 2; ++m) { int rp = wm * 32 + m * 16 + frow;
      aF0[m][0] = RDF(s0, rp, 0); aF0[m][1] = RDF(s0, rp, 1); }
#pragma unroll
    for (int n = 0; n < 4; ++n) { int rp = wn * 64 + n * 16 + frow;
      wG[n][0] = RDF(s0 + 32768, rp, 0); wG[n][1] = RDF(s0 + 32768, rp, 1); }
    stageA(s0, 1, 0);   // Ah1[0]
    stageW(s0, 1, 0);   // U[0]
    stageA(s1, 0, 1);   // Ah0[1]
    stageW(s1, 0, 1);   // G[1]
  }

  for (int kt = 0; kt < NT; ++kt) {
    char* sb = smem + (kt & 1) * 65536;
    char* so = smem + ((kt & 1) ^ 1) * 65536;

    // ========== region A: g-MFMAs ==========
    if (kt + 1 < NT) { WAITV(4); } else { WAITV(0); }
    BAR();
#pragma unroll
    for (int m = 0; m < 2; ++m) { int rp = wm * 32 + m * 16 + frow;
      aF1[m][0] = RDF(sb + 16384, rp, 0); aF1[m][1] = RDF(sb + 16384, rp, 1); }
    __builtin_amdgcn_s_setprio(1);
#pragma unroll
    for (int n = 0; n < 4; ++n)
#pragma unroll
      for (int m = 0; m < 2; ++m) {
        accg[m][n] = MFMA(aF0[m][0], wG[n][0], accg[m][n]);
        accg[m][n] = MFMA(aF0[m][1], wG[n][1], accg[m][n]);
      }
    __builtin_amdgcn_s_setprio(0);
    if (kt + 1 < NT) { stageA(so, 1, kt + 1); stageW(so, 1, kt + 1); }
    __builtin_amdgcn_s_setprio(1);
#pragma unroll
    for (int n = 0; n < 4; ++n)
#pragma unroll
      for (int m = 0; m < 2; ++m) {
        accg[2 + m][n] = MFMA(aF1[m][0], wG[n][0], accg[2 + m][n]);
        accg[2 + m][n] = MFMA(aF1[m][1], wG[n][1], accg[2 + m][n]);
      }
    __builtin_amdgcn_s_setprio(0);
#pragma unroll
    for (int n = 0; n < 4; ++n) { int rp = wn * 64 + n * 16 + frow;
      wU[n][0] = RDF(sb + 49152, rp, 0); wU[n][1] = RDF(sb + 49152, rp, 1); }

    // ========== region B: u-MFMAs ==========
    if (kt + 1 < NT) { WAITV(4); } else { WAITV(0); }
    BAR();
    __builtin_amdgcn_s_setprio(1);
#pragma unroll
    for (int n = 0; n < 4; ++n)
#pragma unroll
      for (int m = 0; m < 2; ++m) {
        accu[m][n] = MFMA(aF0[m][0], wU[n][0], accu[m][n]);
        accu[m][n] = MFMA(aF0[m][1], wU[n][1], accu[m][n]);
      }
    __builtin_amdgcn_s_setprio(0);
    if (kt + 2 < NT) { stageA(sb, 0, kt + 2); stageW(sb, 0, kt + 2); }
    if (kt + 1 < NT) {
#pragma unroll
      for (int m = 0; m < 2; ++m) { int rp = wm * 32 + m * 16 + frow;
        aF0[m][0] = RDF(so, rp, 0); aF0[m][1] = RDF(so, rp, 1); }
    }
    __builtin_amdgcn_s_setprio(1);
#pragma unroll
    for (int n = 0; n < 4; ++n)
#pragma unroll
      for (int m = 0; m < 2; ++m) {
        accu[2 + m][n] = MFMA(aF1[m][0], wU[n][0], accu[2 + m][n]);
        accu[2 + m][n] = MFMA(aF1[m][1], wU[n][1], accu[2 + m][n]);
      }
    __builtin_amdgcn_s_setprio(0);
    if (kt + 1 < NT) {
#pragma unroll
      for (int n = 0; n < 4; ++n) { int rp = wn * 64 + n * 16 + frow;
        wG[n][0] = RDF(so + 32768, rp, 0); wG[n][1] = RDF(so + 32768, rp, 1); }
    }
  }

  // epilogue: silu(g)*u -> bf16 act
  const int orow0 = m0 + wm * 64 + (lane >> 4) * 4;
  const int ocol0 = blockIdx.x * 128 + wn * 64 + frow;
#pragma unroll
  for (int m = 0; m < 4; ++m)
#pragma unroll
    for (int n = 0; n < 4; ++n)
#pragma unroll
      for (int j = 0; j < 4; ++j) {
        float g = accg[m][n][j];
        float u = accu[m][n][j];
        float s = g / (1.0f + __expf(-g));
        act[(size_t)(orow0 + m * 16 + j) * IDIM + (ocol0 + n * 16)] = (__bf16)(s * u);
      }
}

// ===========================================================================
// Pipelined down GEMM: out = act . Dw^T (f32). BM=256 x BN=256, BK=64.
// Identical merged-region skeleton (bN0/bN1 in the wG/wU roles), same
// stage-after-batch-1 ordering (round-14 best).
// ===========================================================================
__global__ __launch_bounds__(512, 2) void down8_kernel(
    const __bf16* __restrict__ act, const __bf16* __restrict__ Dw,
    float* __restrict__ out)
{
  extern __shared__ char smem[];
  const int tid  = threadIdx.x;
  const int lane = tid & 63;
  const int wave = tid >> 6;
  const int wm = wave >> 1, wc = wave & 1;
  const int e  = blockIdx.z;
  const int m0 = e * CHUNK + blockIdx.y * 256;   // row into act/out
  const int n0 = e * HDIM  + blockIdx.x * 256;   // row into Dw

  int su[2], skk[2];
#pragma unroll
  for (int j = 0; j < 2; ++j) {
    int P = j * 8192 + tid * 16;
    int L = P ^ (((P >> 7) & 7) << 4);
    su[j]  = L >> 7;
    skk[j] = (L & 127) >> 1;
  }
  const int ldsw = wave * 1024;

  auto stageA = [&](char* bb, int h, int kt2) {
#pragma unroll
    for (int j = 0; j < 2; ++j) {
      int u = su[j];
      int r = (u & 31) + h * 32 + (u >> 5) * 64;
      const __bf16* src = act + (size_t)(m0 + r) * IDIM + kt2 * 64 + skk[j];
      GLDS16(src, bb + h * 16384 + j * 8192 + ldsw);
    }
  };
  auto stageB = [&](char* bb, int h, int kt2) {   // Dw half h
#pragma unroll
    for (int j = 0; j < 2; ++j) {
      int u = su[j];
      int r = (u & 63) + h * 64 + (u >> 6) * 128;
      const __bf16* src = Dw + (size_t)(n0 + r) * IDIM + kt2 * 64 + skk[j];
      GLDS16(src, bb + 32768 + h * 16384 + j * 8192 + ldsw);
    }
  };

  f32x4 accn0[4][4], accn1[4][4];
#pragma unroll
  for (int m = 0; m < 4; ++m)
#pragma unroll
    for (int n = 0; n < 4; ++n)
#pragma unroll
      for (int j = 0; j < 4; ++j) { accn0[m][n][j] = 0.f; accn1[m][n][j] = 0.f; }

  const int frow = lane & 15;
  const int q16  = (lane >> 4) * 16;
  const int NT   = IDIM / 64;   // 128

  bf16x8 aF0[2][2], aF1[2][2], bN0[4][2], bN1[4][2];

  {
    char* s0 = smem;
    char* s1 = smem + 65536;
    stageA(s0, 0, 0); stageB(s0, 0, 0);
    WAITV(0);
    BAR();
#pragma unroll
    for (int m = 0; m < 2; ++m) { int rp = wm * 32 + m * 16 + frow;
      aF0[m][0] = RDF(s0, rp, 0); aF0[m][1] = RDF(s0, rp, 1); }
#pragma unroll
    for (int n = 0; n < 4; ++n) { int rp = wc * 64 + n * 16 + frow;
      bN0[n][0] = RDF(s0 + 32768, rp, 0); bN0[n][1] = RDF(s0 + 32768, rp, 1); }
    stageA(s0, 1, 0);   // Ah1[0]
    stageB(s0, 1, 0);   // B1[0]
    stageA(s1, 0, 1);   // Ah0[1]
    stageB(s1, 0, 1);   // B0[1]
  }

  for (int kt = 0; kt < NT; ++kt) {
    char* sb = smem + (kt & 1) * 65536;
    char* so = smem + ((kt & 1) ^ 1) * 65536;

    // ========== region A ==========
    if (kt + 1 < NT) { WAITV(4); } else { WAITV(0); }
    BAR();
#pragma unroll
    for (int m = 0; m < 2; ++m) { int rp = wm * 32 + m * 16 + frow;
      aF1[m][0] = RDF(sb + 16384, rp, 0); aF1[m][1] = RDF(sb + 16384, rp, 1); }
    __builtin_amdgcn_s_setprio(1);
#pragma unroll
    for (int n = 0; n < 4; ++n)
#pragma unroll
      for (int m = 0; m < 2; ++m) {
        accn0[m][n] = MFMA(aF0[m][0], bN0[n][0], accn0[m][n]);
        accn0[m][n] = MFMA(aF0[m][1], bN0[n][1], accn0[m][n]);
      }
    __builtin_amdgcn_s_setprio(0);
    if (kt + 1 < NT) { stageA(so, 1, kt + 1); stageB(so, 1, kt + 1); }
    __builtin_amdgcn_s_setprio(1);
#pragma unroll
    for (int n = 0; n < 4; ++n)
#pragma unroll
      for (int m = 0; m < 2; ++m) {
        accn0[2 + m][n] = MFMA(aF1[m][0], bN0[n][0], accn0[2 + m][n]);
        accn0[2 + m][n] = MFMA(aF1[m][1], bN0[n][1], accn0[2 + m][n]);
      }
    __builtin_amdgcn_s_setprio(0);
#pragma unroll
    for (int n = 0; n < 4; ++n) { int rp = wc * 64 + n * 16 + frow;
      bN1[n][0] = RDF(sb + 49152, rp, 0); bN1[n][1] = RDF(sb + 49152, rp, 1); }

    // ========== region B ==========
    if (kt + 1 < NT) { WAITV(4); } else { WAITV(0); }
    BAR();
    __builtin_amdgcn_s_setprio(1);
#pragma unroll
    for (int n = 0; n < 4; ++n)
#pragma unroll
      for (int m = 0; m < 2; ++m) {
        accn1[m][n] = MFMA(aF0[m][0], bN1[n][0], accn1[m][n]);
        accn1[m][n] = MFMA(aF0[m][1], bN1[n][1], accn1[m][n]);
      }
    __builtin_amdgcn_s_setprio(0);
    if (kt + 2 < NT) { stageA(sb, 0, kt + 2); stageB(sb, 0, kt + 2); }
    if (kt + 1 < NT) {
#pragma unroll
      for (int m = 0; m < 2; ++m) { int rp = wm * 32 + m * 16 + frow;
        aF0[m][0] = RDF(so, rp, 0); aF0[m][1] = RDF(so, rp, 1); }
    }
    __builtin_amdgcn_s_setprio(1);
#pragma unroll
    for (int n = 0; n < 4; ++n)
#pragma unroll
      for (int m = 0; m < 2; ++m) {
        accn1[2 + m][n] = MFMA(aF1[m][0], bN1[n][0], accn1[2 + m][n]);
        accn1[2 + m][n] = MFMA(aF1[m][1], bN1[n][1], accn1[2 + m][n]);
      }
    __builtin_amdgcn_s_setprio(0);
    if (kt + 1 < NT) {
#pragma unroll
      for (int n = 0; n < 4; ++n) { int rp = wc * 64 + n * 16 + frow;
        bN0[n][0] = RDF(so + 32768, rp, 0); bN0[n][1] = RDF(so + 32768, rp, 1); }
    }
  }

  const int orow0 = m0 + wm * 64 + (lane >> 4) * 4;
  const int ocol0 = blockIdx.x * 256 + wc * 128 + frow;
#pragma unroll
  for (int m = 0; m < 4; ++m)
#pragma unroll
    for (int n = 0; n < 4; ++n)
#pragma unroll
      for (int j = 0; j < 4; ++j) {
        out[(size_t)(orow0 + m * 16 + j) * HDIM + (ocol0 + n * 16)] = accn0[m][n][j];
        out[(size_t)(orow0 + m * 16 + j) * HDIM + (ocol0 + 64 + n * 16)] = accn1[m][n][j];
      }
}

// ===========================================================================
// Fallback: round-3 kernels (128^2 2-barrier, per-expert) if ws is small.
// ===========================================================================
__global__ __launch_bounds__(256) void gateup2_kernel(
    const __bf16* __restrict__ X, const __bf16* __restrict__ Gw,
    const __bf16* __restrict__ Uw, __bf16* __restrict__ act)
{
  __shared__ __bf16 lds[2][3][128 * 32];
  const int tid  = threadIdx.x;
  const int lane = tid & 63;
  const int wave = tid >> 6;
  const int wr = wave >> 1, wc = wave & 1;
  const int m0 = blockIdx.x * 128;
  const int n0 = blockIdx.y * 128;

  int srow[2], scol[2];
#pragma unroll
  for (int h = 0; h < 2; ++h) {
    const int B  = h * 4096 + tid * 16;
    const int Bs = B ^ (((B >> 7) & 3) << 4);
    srow[h] = Bs >> 6;
    scol[h] = (Bs & 63) >> 1;
  }
  const int ldst_off[2] = { wave * 1024, 4096 + wave * 1024 };

  f32x4 accg[4][4], accu[4][4];
#pragma unroll
  for (int m = 0; m < 4; ++m)
#pragma unroll
    for (int n = 0; n < 4; ++n)
#pragma unroll
      for (int j = 0; j < 4; ++j) { accg[m][n][j] = 0.f; accu[m][n][j] = 0.f; }

  const int frow  = lane & 15;
  const int rdoff = ((lane >> 4) * 16) ^ (((frow >> 1) & 3) << 4);

  auto stage = [&](int buf, int kt) {
    const int k0 = kt * 32;
#pragma unroll
    for (int h = 0; h < 2; ++h) {
      GLDS16(X  + (size_t)(m0 + srow[h]) * HDIM + k0 + scol[h], (char*)&lds[buf][0][0] + ldst_off[h]);
      GLDS16(Gw + (size_t)(n0 + srow[h]) * HDIM + k0 + scol[h], (char*)&lds[buf][1][0] + ldst_off[h]);
      GLDS16(Uw + (size_t)(n0 + srow[h]) * HDIM + k0 + scol[h], (char*)&lds[buf][2][0] + ldst_off[h]);
    }
  };

  const int NT = HDIM / 32;
  stage(0, 0);
  int cur = 0;
  for (int kt = 0; kt < NT; ++kt) {
    __syncthreads();
    if (kt + 1 < NT) stage(cur ^ 1, kt + 1);
    const char* bA = (const char*)&lds[cur][0][0];
    const char* bG = (const char*)&lds[cur][1][0];
    const char* bU = (const char*)&lds[cur][2][0];
    bf16x8 af[4];
#pragma unroll
    for (int m = 0; m < 4; ++m)
      af[m] = *(const bf16x8*)(bA + (wr * 64 + m * 16 + frow) * 64 + rdoff);
#pragma unroll
    for (int n = 0; n < 4; ++n) {
      bf16x8 bg = *(const bf16x8*)(bG + (wc * 64 + n * 16 + frow) * 64 + rdoff);
      bf16x8 bu = *(const bf16x8*)(bU + (wc * 64 + n * 16 + frow) * 64 + rdoff);
#pragma unroll
      for (int m = 0; m < 4; ++m) {
        accg[m][n] = MFMA(af[m], bg, accg[m][n]);
        accu[m][n] = MFMA(af[m], bu, accu[m][n]);
      }
    }
    cur ^= 1;
  }
  const int orow = m0 + wr * 64 + (lane >> 4) * 4;
  const int ocol = n0 + wc * 64 + (lane & 15);
#pragma unroll
  for (int m = 0; m < 4; ++m)
#pragma unroll
    for (int n = 0; n < 4; ++n)
#pragma unroll
      for (int j = 0; j < 4; ++j) {
        float g = accg[m][n][j];
        float u = accu[m][n][j];
        float s = g / (1.0f + __expf(-g));
        act[(size_t)(orow + m * 16 + j) * IDIM + (ocol + n * 16)] = (__bf16)(s * u);
      }
}

__global__ __launch_bounds__(256) void down2_kernel(
    const __bf16* __restrict__ act, const __bf16* __restrict__ Dw,
    float* __restrict__ out)
{
  __shared__ __bf16 lds[2][2][128 * 32];
  const int tid  = threadIdx.x;
  const int lane = tid & 63;
  const int wave = tid >> 6;
  const int wr = wave >> 1, wc = wave & 1;
  const int m0 = blockIdx.x * 128;
  const int n0 = blockIdx.y * 128;

  int srow[2], scol[2];
#pragma unroll
  for (int h = 0; h < 2; ++h) {
    const int B  = h * 4096 + tid * 16;
    const int Bs = B ^ (((B >> 7) & 3) << 4);
    srow[h] = Bs >> 6;
    scol[h] = (Bs & 63) >> 1;
  }
  const int ldst_off[2] = { wave * 1024, 4096 + wave * 1024 };

  f32x4 acc[4][4];
#pragma unroll
  for (int m = 0; m < 4; ++m)
#pragma unroll
    for (int n = 0; n < 4; ++n)
#pragma unroll
      for (int j = 0; j < 4; ++j) acc[m][n][j] = 0.f;

  const int frow  = lane & 15;
  const int rdoff = ((lane >> 4) * 16) ^ (((frow >> 1) & 3) << 4);

  auto stage = [&](int buf, int kt) {
    const int k0 = kt * 32;
#pragma unroll
    for (int h = 0; h < 2; ++h) {
      GLDS16(act + (size_t)(m0 + srow[h]) * IDIM + k0 + scol[h], (char*)&lds[buf][0][0] + ldst_off[h]);
      GLDS16(Dw  + (size_t)(n0 + srow[h]) * IDIM + k0 + scol[h], (char*)&lds[buf][1][0] + ldst_off[h]);
    }
  };

  const int NT = IDIM / 32;
  stage(0, 0);
  int cur = 0;
  for (int kt = 0; kt < NT; ++kt) {
    __syncthreads();
    if (kt + 1 < NT) stage(cur ^ 1, kt + 1);
    const char* bA = (const char*)&lds[cur][0][0];
    const char* bW = (const char*)&lds[cur][1][0];
    bf16x8 af[4];
#pragma unroll
    for (int m = 0; m < 4; ++m)
      af[m] = *(const bf16x8*)(bA + (wr * 64 + m * 16 + frow) * 64 + rdoff);
#pragma unroll
    for (int n = 0; n < 4; ++n) {
      bf16x8 bw = *(const bf16x8*)(bW + (wc * 64 + n * 16 + frow) * 64 + rdoff);
#pragma unroll
      for (int m = 0; m < 4; ++m)
        acc[m][n] = MFMA(af[m], bw, acc[m][n]);
    }
    cur ^= 1;
  }
  const int orow = m0 + wr * 64 + (lane >> 4) * 4;
  const int ocol = n0 + wc * 64 + (lane & 15);
#pragma unroll
  for (int m = 0; m < 4; ++m)
#pragma unroll
    for (int n = 0; n < 4; ++n)
#pragma unroll
      for (int j = 0; j < 4; ++j)
        out[(size_t)(orow + m * 16 + j) * HDIM + (ocol + n * 16)] = acc[m][n][j];
}

// ---------------------------------------------------------------------------
extern "C" void kernel_launch(void* const* d_in, const int* in_sizes, int n_in,
                              void* d_out, int out_size, void* d_ws, size_t ws_size,
                              hipStream_t stream)
{
  const float* hidden = (const float*)d_in[0];
  const float* gate_w = (const float*)d_in[1];
  const float* up_w   = (const float*)d_in[2];
  const float* down_w = (const float*)d_in[3];
  float* out = (float*)d_out;

  const size_t SZ_X    = (size_t)32768 * HDIM;
  const size_t SZ_Wall = (size_t)E_NUM * IDIM * HDIM;
  const size_t SZ_ACT  = (size_t)32768 * IDIM;
  const size_t need8 = (SZ_X + 3 * SZ_Wall + SZ_ACT) * sizeof(__bf16);  // ~1.48 GB

  if (ws_size >= need8) {
    __bf16* xb  = (__bf16*)d_ws;
    __bf16* gwb = xb  + SZ_X;
    __bf16* uwb = gwb + SZ_Wall;
    __bf16* dwb = uwb + SZ_Wall;
    __bf16* actb = dwb + SZ_Wall;

    cvt_kernel<<<SZ_X    / 2048, 256, 0, stream>>>(hidden, xb);
    cvt_kernel<<<SZ_Wall / 2048, 256, 0, stream>>>(gate_w, gwb);
    cvt_kernel<<<SZ_Wall / 2048, 256, 0, stream>>>(up_w,   uwb);
    cvt_kernel<<<SZ_Wall / 2048, 256, 0, stream>>>(down_w, dwb);

    gateup8_kernel<<<dim3(IDIM / 128, CHUNK / 256, E_NUM), 512, 131072, stream>>>(xb, gwb, uwb, actb);
    down8_kernel  <<<dim3(HDIM / 256, CHUNK / 256, E_NUM), 512, 131072, stream>>>(actb, dwb, out);
  } else {
    const size_t sX = (size_t)CHUNK * HDIM;
    const size_t sW = (size_t)IDIM * HDIM;
    __bf16* xb = (__bf16*)d_ws;
    __bf16* gb = xb + sX;
    __bf16* ub = gb + sW;
    __bf16* db = ub + sW;
    __bf16* act = db + sW;
    for (int e = 0; e < E_NUM; ++e) {
      const float* Xe = hidden + (size_t)e * sX;
      const float* Ge = gate_w + (size_t)e * sW;
      const float* Ue = up_w   + (size_t)e * sW;
      const float* De = down_w + (size_t)e * sW;
      float* Oe = out + (size_t)e * CHUNK * HDIM;
      cvt_kernel<<<sX / 2048, 256, 0, stream>>>(Xe, xb);
      cvt_kernel<<<sW / 2048, 256, 0, stream>>>(Ge, gb);
      cvt_kernel<<<sW / 2048, 256, 0, stream>>>(Ue, ub);
      cvt_kernel<<<sW / 2048, 256, 0, stream>>>(De, db);
      gateup2_kernel<<<dim3(CHUNK / 128, IDIM / 128), 256, 0, stream>>>(xb, gb, ub, act);
      down2_kernel<<<dim3(CHUNK / 128, HDIM / 128), 256, 0, stream>>>(act, db, Oe);
    }
  }
}